// Round 5
// baseline (6664.825 us; speedup 1.0000x reference)
//
#include <hip/hip_runtime.h>
#include <stdint.h>

#define NSAMP 400
#define NC 512

#if __has_builtin(__builtin_amdgcn_exp2f)
#define EXP2F(x) __builtin_amdgcn_exp2f(x)
#else
#define EXP2F(x) __expf((x) * 0.6931471805599453f)
#endif
#if __has_builtin(__builtin_amdgcn_logf)
#define LOG2F(x) __builtin_amdgcn_logf(x)
#else
#define LOG2F(x) (__logf(x) * 1.4426950408889634f)
#endif

// Guaranteed single-instruction rotate: alignbit(v,v,32-n) == rotl(v,n).
static __device__ __forceinline__ uint32_t rotl32(uint32_t v, int n) {
  return __builtin_amdgcn_alignbit(v, v, (uint32_t)(32 - n));
}

// Guaranteed v_add3_u32 (a + b + c), c wave-uniform (SGPR).
static __device__ __forceinline__ uint32_t add3s(uint32_t a, uint32_t b, uint32_t c) {
  uint32_t d;
  asm("v_add3_u32 %0, %1, %2, %3" : "=v"(d) : "v"(a), "v"(b), "s"(c));
  return d;
}

// Full threefry2x32 (setup only; per-thread keys -> plain C, no asm).
#define TFS(x0, x1, R) { x0 += x1; x1 = rotl32(x1, R); x1 ^= x0; }
static __device__ __forceinline__ void threefry2x32_full(
    uint32_t k0, uint32_t k1, uint32_t x0, uint32_t x1,
    uint32_t& o0, uint32_t& o1)
{
  const uint32_t ks2 = k0 ^ k1 ^ 0x1BD11BDAu;
  x0 += k0; x1 += k1;
  TFS(x0,x1,13) TFS(x0,x1,15) TFS(x0,x1,26) TFS(x0,x1, 6)
  x0 += k1; x1 += ks2 + 1u;
  TFS(x0,x1,17) TFS(x0,x1,29) TFS(x0,x1,16) TFS(x0,x1,24)
  x0 += ks2; x1 += k0 + 2u;
  TFS(x0,x1,13) TFS(x0,x1,15) TFS(x0,x1,26) TFS(x0,x1, 6)
  x0 += k0; x1 += k1 + 3u;
  TFS(x0,x1,17) TFS(x0,x1,29) TFS(x0,x1,16) TFS(x0,x1,24)
  x0 += k1; x1 += ks2 + 4u;
  TFS(x0,x1,13) TFS(x0,x1,15) TFS(x0,x1,26) TFS(x0,x1, 6)
  x0 += ks2; x1 += k0 + 5u;
  o0 = x0; o1 = x1;
}

// ---------------------------------------------------------------------------
// JAX *partitionable* threefry per element: bits(i) = x0f ^ x1f of
// cipher(key_s, data=(0, i)).  Verified bit-exact (absmax 6.1e-5, rounds 0/4).
// Op-minimized, stream-identical:
//  - round-1 add folded into init
//  - injections 1-4 fused with the next round's add (forced v_add3_u32)
//  - all rotates forced to v_alignbit_b32
// Keys/injections are wave-uniform SGPRs.
// ---------------------------------------------------------------------------
#define R3OP(R)          { x0 += x1; x1 = rotl32(x1, R) ^ x0; }
#define INJR(ka, kb, R)  { x1 += kb; x0 = add3s(x0, x1, ka); x1 = rotl32(x1, R) ^ x0; }

static __device__ __forceinline__ uint32_t tf_bits_fused(
    uint32_t k0, uint32_t k1, uint32_t ks2,
    uint32_t I1, uint32_t I2, uint32_t I3, uint32_t I4, uint32_t I5,
    uint32_t cnt)
{
  uint32_t x1 = cnt + k1;
  uint32_t x0 = x1 + k0;              // == x0_init(k0) + x1  (round-1 add)
  x1 = rotl32(x1, 13) ^ x0;           // round 1 tail
  R3OP(15) R3OP(26) R3OP(6)
  INJR(k1,  I1, 17) R3OP(29) R3OP(16) R3OP(24)
  INJR(ks2, I2, 13) R3OP(15) R3OP(26) R3OP(6)
  INJR(k0,  I3, 17) R3OP(29) R3OP(16) R3OP(24)
  INJR(k1,  I4, 13) R3OP(15) R3OP(26) R3OP(6)
  x0 += ks2; x1 += I5;                // final injection
  return x0 ^ x1;                     // JAX partitionable 32-bit fold
}

// bits -> u in [-0.99999994, 1) (bit-exact JAX uniform) -> L = log2(1-u^2)
static __device__ __forceinline__ void bits2uL(uint32_t bits, float& u, float& L) {
  float f = __uint_as_float(__builtin_amdgcn_alignbit(0x7Fu, bits, 9u)) - 1.0f;
  u = fmaf(f, 2.0f, -0.99999994f);     // max(lo,.) provably identity
  L = LOG2F(fmaf(u, -u, 1.0f));
}

// erfinv (Giles/XLA coefficients) on log2 basis fused with exp2.
static __device__ __forceinline__ float softexp(float u, float L, float sd2, float m2) {
  float p;
  if (__builtin_expect(L > -7.2134752f, 1)) {  // central branch (99.7%/lane)
    float w = fmaf(L, -0.69314718f, -2.5f);
    p =              2.81022636e-08f;
    p = fmaf(p, w,   3.43273939e-07f);
    p = fmaf(p, w,  -3.5233877e-06f);
    p = fmaf(p, w,  -4.39150654e-06f);
    p = fmaf(p, w,   0.00021858087f);
    p = fmaf(p, w,  -0.00125372503f);
    p = fmaf(p, w,  -0.00417768164f);
    p = fmaf(p, w,   0.246640727f);
    p = fmaf(p, w,   1.50140941f);
  } else {                                   // tail, ~0.34%/lane
    float w = __builtin_amdgcn_sqrtf(L * -0.69314718f) - 3.0f;
    p =             -0.000200214257f;
    p = fmaf(p, w,   0.000100950558f);
    p = fmaf(p, w,   0.00134934322f);
    p = fmaf(p, w,  -0.00367342844f);
    p = fmaf(p, w,   0.00573950773f);
    p = fmaf(p, w,  -0.0076224613f);
    p = fmaf(p, w,   0.00943887047f);
    p = fmaf(p, w,   1.00167406f);
    p = fmaf(p, w,   2.83297682f);
  }
  float px = p * u;
  return EXP2F(fmaf(px, sd2, m2));
}

static __device__ __forceinline__ uint32_t rfl(uint32_t x) {
  return (uint32_t)__builtin_amdgcn_readfirstlane((int)x);
}

// Wave64 sum via DPP (row_shr 1/2/4/8, row_bcast 15/31), total in lane 63.
template <int CTRL>
static __device__ __forceinline__ float dppadd(float x) {
  return x + __int_as_float(
      __builtin_amdgcn_update_dpp(0, __float_as_int(x), CTRL, 0xf, 0xf, false));
}
static __device__ __forceinline__ float wave_sum_bcast(float x) {
  x = dppadd<0x111>(x);   // row_shr:1
  x = dppadd<0x112>(x);   // row_shr:2
  x = dppadd<0x114>(x);   // row_shr:4
  x = dppadd<0x118>(x);   // row_shr:8
  x = dppadd<0x142>(x);   // row_bcast:15
  x = dppadd<0x143>(x);   // row_bcast:31
  return __uint_as_float((uint32_t)__builtin_amdgcn_readlane(__float_as_int(x), 63));
}

// One wave per row; 8 columns per lane; 4 waves/block.  Sample loop unrolled
// x2 with A/B phase interleave; kc reads for the NEXT pair are issued right
// after the current keys are extracted, so their lgkmcnt wait has a full
// iteration (~1400 cy) of cover.
__global__ __launch_bounds__(256)
void mc_softmax_kernel(const float* __restrict__ mean,
                       const float* __restrict__ var,
                       float* __restrict__ out)
{
  // Per-sample constant table (JAX fold-like split: key_s = both words of
  // cipher((0,42),(0,s)) — verified bit-exact rounds 0/4):
  // [s] = {k0, k1, ks2, ks2+1, k0+2, k1+3, ks2+4, k0+5}
  __shared__ __align__(16) uint32_t kc[NSAMP][8];
  for (int s = threadIdx.x; s < NSAMP; s += 256) {
    uint32_t a, b;
    threefry2x32_full(0u, 42u, 0u, (uint32_t)s, a, b);
    uint32_t ks2 = a ^ b ^ 0x1BD11BDAu;
    kc[s][0] = a;        kc[s][1] = b;
    kc[s][2] = ks2;      kc[s][3] = ks2 + 1u;
    kc[s][4] = a + 2u;   kc[s][5] = b + 3u;
    kc[s][6] = ks2 + 4u; kc[s][7] = a + 5u;
  }
  __syncthreads();

  const int lane  = threadIdx.x & 63;
  const int row   = (blockIdx.x << 2) + (threadIdx.x >> 6);
  const int cbase = lane << 2;

  const float* mr = mean + (size_t)row * NC;
  const float* vr = var  + (size_t)row * NC;

  float m2[8], sd2[8], acc[8];
  {
    const float L2E = 1.4426950408889634f;   // log2(e)
    const float S2L = 2.0402788959f;         // sqrt(2)*log2(e)
    float4 t0 = *(const float4*)(mr + cbase);
    float4 t1 = *(const float4*)(mr + 256 + cbase);
    m2[0] = t0.x * L2E; m2[1] = t0.y * L2E; m2[2] = t0.z * L2E; m2[3] = t0.w * L2E;
    m2[4] = t1.x * L2E; m2[5] = t1.y * L2E; m2[6] = t1.z * L2E; m2[7] = t1.w * L2E;
    float4 v0 = *(const float4*)(vr + cbase);
    float4 v1 = *(const float4*)(vr + 256 + cbase);
    sd2[0] = __builtin_amdgcn_sqrtf(v0.x) * S2L;
    sd2[1] = __builtin_amdgcn_sqrtf(v0.y) * S2L;
    sd2[2] = __builtin_amdgcn_sqrtf(v0.z) * S2L;
    sd2[3] = __builtin_amdgcn_sqrtf(v0.w) * S2L;
    sd2[4] = __builtin_amdgcn_sqrtf(v1.x) * S2L;
    sd2[5] = __builtin_amdgcn_sqrtf(v1.y) * S2L;
    sd2[6] = __builtin_amdgcn_sqrtf(v1.z) * S2L;
    sd2[7] = __builtin_amdgcn_sqrtf(v1.w) * S2L;
  }
#pragma unroll
  for (int j = 0; j < 8; ++j) acc[j] = 0.0f;

  const uint32_t base = (uint32_t)(row * NC + cbase);
  uint32_t cnt[8];
#pragma unroll
  for (int j = 0; j < 4; ++j) { cnt[j] = base + (uint32_t)j; cnt[4+j] = base + 256u + (uint32_t)j; }

  // Prefetch registers for the kc rows of the current sample pair.
  uint4 pa0 = *(const uint4*)&kc[0][0];
  uint4 pa1 = *(const uint4*)&kc[0][4];
  uint4 pb0 = *(const uint4*)&kc[1][0];
  uint4 pb1 = *(const uint4*)&kc[1][4];

  for (int s = 0; s < NSAMP; s += 2) {
    // Extract current keys to SGPRs (wave-uniform).
    const uint32_t Ak0 = rfl(pa0.x), Ak1 = rfl(pa0.y), Aks = rfl(pa0.z), AI1 = rfl(pa0.w);
    const uint32_t AI2 = rfl(pa1.x), AI3 = rfl(pa1.y), AI4 = rfl(pa1.z), AI5 = rfl(pa1.w);
    const uint32_t Bk0 = rfl(pb0.x), Bk1 = rfl(pb0.y), Bks = rfl(pb0.z), BI1 = rfl(pb0.w);
    const uint32_t BI2 = rfl(pb1.x), BI3 = rfl(pb1.y), BI4 = rfl(pb1.z), BI5 = rfl(pb1.w);

    // Issue next pair's kc reads now; they complete under this iteration.
    const int sn = (s + 2 < NSAMP) ? s + 2 : 0;   // wrap harmlessly on last iter
    pa0 = *(const uint4*)&kc[sn][0];
    pa1 = *(const uint4*)&kc[sn][4];
    pb0 = *(const uint4*)&kc[sn + 1][0];
    pb1 = *(const uint4*)&kc[sn + 1][4];

    // ---- A phase 1: 8 independent cipher -> u -> log chains (branch-free)
    float uA[8], LA[8];
#pragma unroll
    for (int j = 0; j < 8; ++j) {
      uint32_t bits = tf_bits_fused(Ak0, Ak1, Aks, AI1, AI2, AI3, AI4, AI5, cnt[j]);
      bits2uL(bits, uA[j], LA[j]);
    }
    // ---- A phase 2: branchy erfinv-poly + exp2
    float eA[8];
#pragma unroll
    for (int j = 0; j < 8; ++j) eA[j] = softexp(uA[j], LA[j], sd2[j], m2[j]);
    const float sA = ((eA[0] + eA[1]) + (eA[2] + eA[3]))
                   + ((eA[4] + eA[5]) + (eA[6] + eA[7]));

    // ---- B phase 1 (branch-free region; A's reduction scheduled into it)
    float uB[8], LB[8];
#pragma unroll
    for (int j = 0; j < 8; ++j) {
      uint32_t bits = tf_bits_fused(Bk0, Bk1, Bks, BI1, BI2, BI3, BI4, BI5, cnt[j]);
      bits2uL(bits, uB[j], LB[j]);
    }

    // ---- A reduce + accumulate (overlaps with B phase 1 chains)
    const float invA = __builtin_amdgcn_rcpf(wave_sum_bcast(sA));
#pragma unroll
    for (int j = 0; j < 8; ++j) acc[j] = fmaf(eA[j], invA, acc[j]);

    // ---- B phase 2
    float eB[8];
#pragma unroll
    for (int j = 0; j < 8; ++j) eB[j] = softexp(uB[j], LB[j], sd2[j], m2[j]);
    const float sB = ((eB[0] + eB[1]) + (eB[2] + eB[3]))
                   + ((eB[4] + eB[5]) + (eB[6] + eB[7]));

    // ---- B reduce + accumulate
    const float invB = __builtin_amdgcn_rcpf(wave_sum_bcast(sB));
#pragma unroll
    for (int j = 0; j < 8; ++j) acc[j] = fmaf(eB[j], invB, acc[j]);
  }

  float* orow = out + (size_t)row * NC;
  const float sc = 1.0f / (float)NSAMP;
  float4 o0, o1;
  o0.x = acc[0] * sc; o0.y = acc[1] * sc; o0.z = acc[2] * sc; o0.w = acc[3] * sc;
  o1.x = acc[4] * sc; o1.y = acc[5] * sc; o1.z = acc[6] * sc; o1.w = acc[7] * sc;
  *(float4*)(orow + cbase)       = o0;
  *(float4*)(orow + 256 + cbase) = o1;
}

extern "C" void kernel_launch(void* const* d_in, const int* in_sizes, int n_in,
                              void* d_out, int out_size, void* d_ws, size_t ws_size,
                              hipStream_t stream) {
  const float* mean = (const float*)d_in[0];
  const float* var  = (const float*)d_in[1];
  float* out        = (float*)d_out;

  const int rows = out_size / NC;        // 16384
  const int blocks = rows / 4;           // 4 rows (waves) per 256-thread block
  mc_softmax_kernel<<<blocks, 256, 0, stream>>>(mean, var, out);
}